// Round 10
// baseline (432.891 us; speedup 1.0000x reference)
//
#include <hip/hip_runtime.h>
#include <cstdint>
#include <cstddef>

#define TT 8192
#define DIN 1024
#define DHID 2048
#define DOUT 1024
#define NCHUNK 128
#define CLEN 64   // TT / NCHUNK
#define GBUF 10240  // elems per 20 KB gate sub-tile buffer (A 8KB + 3xB 4KB)

typedef __bf16 bf16x8 __attribute__((ext_vector_type(8)));
typedef float f32x4 __attribute__((ext_vector_type(4)));
using u32_as1 = __attribute__((address_space(1))) const unsigned int;
using u32_as3 = __attribute__((address_space(3))) unsigned int;

__device__ __forceinline__ unsigned short bf16r(float x) {
  unsigned int u = __float_as_uint(x);
  u += 0x7fffu + ((u >> 16) & 1u);
  return (unsigned short)(u >> 16);
}

__device__ __forceinline__ float bf16tof(unsigned int u) {
  return __uint_as_float(u << 16);
}

__global__ void cast_f32_bf16(const float* __restrict__ in, unsigned short* __restrict__ out, int n4) {
  int i = blockIdx.x * 256 + threadIdx.x;
  if (i >= n4) return;
  const float4 v = reinterpret_cast<const float4*>(in)[i];
  ushort4 o;
  o.x = bf16r(v.x);
  o.y = bf16r(v.y);
  o.z = bf16r(v.z);
  o.w = bf16r(v.w);
  reinterpret_cast<ushort4*>(out)[i] = o;
}

// All four weight matrices are exactly 2M elements: one dispatch, y selects the matrix.
__global__ void cast_w4(const float* __restrict__ s0, const float* __restrict__ s1,
                        const float* __restrict__ s2, const float* __restrict__ s3,
                        unsigned short* __restrict__ d0, unsigned short* __restrict__ d1,
                        unsigned short* __restrict__ d2, unsigned short* __restrict__ d3) {
  const int y = blockIdx.y;
  const float* s = (y == 0) ? s0 : ((y == 1) ? s1 : ((y == 2) ? s2 : s3));
  unsigned short* d = (y == 0) ? d0 : ((y == 1) ? d1 : ((y == 2) ? d2 : d3));
  const int i = blockIdx.x * 256 + threadIdx.x;
  const float4 v = reinterpret_cast<const float4*>(s)[i];
  ushort4 o;
  o.x = bf16r(v.x);
  o.y = bf16r(v.y);
  o.z = bf16r(v.z);
  o.w = bf16r(v.w);
  reinterpret_cast<ushort4*>(d)[i] = o;
}

__global__ void dec_kernel(const float* __restrict__ pre_a, float* __restrict__ dec) {
  const int d = blockIdx.x * 256 + threadIdx.x;
  if (d < DHID) dec[d] = -8.0f * log1pf(expf(pre_a[d]));
}

// ---------------- Fused gate GEMM + in-epilogue chunk-aggregate (scan pass1) ----------------
// Main loop = round-8 proven body. Round-9 lesson: the fused epilogue pushed VGPR 128->132,
// crossing the occupancy cliff at 128 (m69) -> 21%->11.5% occupancy, +98 µs. Fixes here:
// (a) __launch_bounds__(256, 4) forces VGPR <= 512/4 = 128 (epilogue-only spill if needed);
// (b) interleaved per-mf shfl composition (no Aseg[4]/Bseg[4] arrays, ~6 extra live regs).
__global__ __launch_bounds__(256, 4) void gemm_gates(
    const unsigned short* __restrict__ X, const unsigned short* __restrict__ Wr,
    const unsigned short* __restrict__ Wi, const unsigned short* __restrict__ Wx,
    const float* __restrict__ br, const float* __restrict__ bi, const float* __restrict__ bx,
    const float* __restrict__ dec, unsigned int* __restrict__ pack_out,
    float* __restrict__ aggA, float* __restrict__ aggB) {
  __shared__ __align__(16) unsigned short lds[2 * GBUF];  // 2 sub-tiles x 20 KB
  const int n0 = blockIdx.x * 64;
  const int t0 = blockIdx.y * 128;
  const int tid = threadIdx.x;
  const int wave = tid >> 6, lane = tid & 63;
  const int wr = wave >> 1, wc = wave & 1;
  const int row16 = lane & 15, kq = lane >> 4;

  f32x4 acc[3][4][2] = {};

  for (int k0 = 0; k0 < DIN; k0 += 64) {
    // Stage BOTH sub-tiles (k0, k0+32): 40 segs of 1 KiB, wave w owns segs 10w..10w+9.
#pragma unroll
    for (int s = 0; s < 10; ++s) {
      const int sg = wave * 10 + s;
      const int half = (sg >= 20);
      const int seg = sg - half * 20;
      const int kk = k0 + half * 32;
      unsigned short* dst = lds + half * GBUF;
      const int lb = lane * 16;
      if (seg < 8) {
        const int off = seg * 1024 + lb;
        const int row = off >> 6, ke = (off & 63) >> 1;
        __builtin_amdgcn_global_load_lds((u32_as1*)(X + (size_t)(t0 + row) * DIN + kk + ke),
                                         (u32_as3*)(dst + seg * 512), 16, 0, 0);
      } else {
        const int m = (seg - 8) >> 2, sub = (seg - 8) & 3;
        const unsigned short* Bm = (m == 0) ? Wr : ((m == 1) ? Wi : Wx);
        const int off = sub * 1024 + lb;
        const int row = off >> 6, ke = (off & 63) >> 1;
        __builtin_amdgcn_global_load_lds((u32_as1*)(Bm + (size_t)(n0 + row) * DIN + kk + ke),
                                         (u32_as3*)(dst + (128 + m * 64) * 32 + sub * 512), 16, 0, 0);
      }
    }
    __syncthreads();

#pragma unroll
    for (int half = 0; half < 2; ++half) {
      const unsigned short* hb = lds + half * GBUF;
      const unsigned short* Ab = hb + (wr * 64 + row16) * 32 + kq * 8;
      bf16x8 af[4];
#pragma unroll
      for (int mf = 0; mf < 4; ++mf) af[mf] = *reinterpret_cast<const bf16x8*>(Ab + mf * 16 * 32);
#pragma unroll
      for (int z = 0; z < 3; ++z) {
        const unsigned short* Bb = hb + (128 + z * 64 + wc * 32 + row16) * 32 + kq * 8;
        const bf16x8 b0 = *reinterpret_cast<const bf16x8*>(Bb);
        const bf16x8 b1 = *reinterpret_cast<const bf16x8*>(Bb + 16 * 32);
#pragma unroll
        for (int mf = 0; mf < 4; ++mf) {
          acc[z][mf][0] = __builtin_amdgcn_mfma_f32_16x16x32_bf16(af[mf], b0, acc[z][mf][0], 0, 0, 0);
          acc[z][mf][1] = __builtin_amdgcn_mfma_f32_16x16x32_bf16(af[mf], b1, acc[z][mf][1], 0, 0, 0);
        }
      }
    }
    __syncthreads();
  }

  // Epilogue: C/D layout col = lane&15, row = (lane>>4)*4 + reg (m89-verified).
  // om = 1-a stored bf16 (scan-safe). Chunk aggregate folded inline in increasing-t order:
  // t = mf*16 + kq*4 + r. Per mf: r-ordered lane fold -> immediate 4-step kq composition
  // via __shfl (lanes (lane&15)+16q). kq==0 lanes write chunk c = 2*blockIdx.y + wr.
#pragma unroll
  for (int nf = 0; nf < 2; ++nf) {
    const int n = n0 + wc * 32 + nf * 16 + row16;
    const float brv = br[n], biv = bi[n], bxv = bx[n], dcv = dec[n];
    float Ac = 1.0f, Bc = 0.0f;
    const int srcbase = lane & 15;
#pragma unroll
    for (int mf = 0; mf < 4; ++mf) {
      float As = 1.0f, Bs = 0.0f;
#pragma unroll
      for (int r = 0; r < 4; ++r) {
        const int t = t0 + wr * 64 + mf * 16 + kq * 4 + r;
        const float rp = acc[0][mf][nf][r] + brv;
        const float ip = acc[1][mf][nf][r] + biv;
        const float xv = acc[2][mf][nf][r] + bxv;
        const float rs = __builtin_amdgcn_rcpf(1.0f + __expf(-rp));
        const float av = __expf(dcv * rs);
        const float is = __builtin_amdgcn_rcpf(1.0f + __expf(-ip));
        const float gv = sqrtf(fmaxf(0.0f, 1.0f - av * av)) * (is * xv);
        const float om = 1.0f - av;
        pack_out[(size_t)t * DHID + n] = ((unsigned int)bf16r(gv) << 16) | (unsigned int)bf16r(om);
        As = av * As;           // r-ordered product
        Bs = fmaf(av, Bs, gv);  // r-ordered affine fold
      }
#pragma unroll
      for (int q = 0; q < 4; ++q) {
        const float Aq = __shfl(As, srcbase + (q << 4), 64);
        const float Bq = __shfl(Bs, srcbase + (q << 4), 64);
        Ac = Aq * Ac;
        Bc = fmaf(Aq, Bc, Bq);
      }
    }
    if (kq == 0) {
      const int c = blockIdx.y * 2 + wr;
      aggA[c * DHID + n] = Ac;
      aggB[c * DHID + n] = Bc;
    }
  }
}

// ---------------- Output projection GEMM (round-8 proven body) ----------------
template <int KDIM, int NDIM>
__global__ __launch_bounds__(256) void gemm_bt(const unsigned short* __restrict__ A,
                                               const unsigned short* __restrict__ B,
                                               const float* __restrict__ bias,
                                               float* __restrict__ out) {
  __shared__ __align__(16) unsigned short Alds[2][128 * 32];
  __shared__ __align__(16) unsigned short Blds[2][128 * 32];
  const int n0 = blockIdx.x * 128;
  const int t0 = blockIdx.y * 128;
  const int tid = threadIdx.x;
  const int wave = tid >> 6, lane = tid & 63;
  const int wr = wave >> 1, wc = wave & 1;
  const int row16 = lane & 15, kq = lane >> 4;

  f32x4 acc[4][4] = {};

  for (int k0 = 0; k0 < KDIM; k0 += 64) {
#pragma unroll
    for (int half = 0; half < 2; ++half) {
      const int kk = k0 + half * 32;
#pragma unroll
      for (int s = 0; s < 2; ++s) {
        const int seg = wave * 2 + s;
        const int off = seg * 1024 + lane * 16;
        const int row = off >> 6;
        const int ke = (off & 63) >> 1;
        __builtin_amdgcn_global_load_lds((u32_as1*)(A + (size_t)(t0 + row) * KDIM + kk + ke),
                                         (u32_as3*)(Alds[half] + seg * 512), 16, 0, 0);
        __builtin_amdgcn_global_load_lds((u32_as1*)(B + (size_t)(n0 + row) * KDIM + kk + ke),
                                         (u32_as3*)(Blds[half] + seg * 512), 16, 0, 0);
      }
    }
    __syncthreads();

#pragma unroll
    for (int half = 0; half < 2; ++half) {
      const unsigned short* Ab = Alds[half] + (wr * 64 + row16) * 32 + kq * 8;
      const unsigned short* Bb = Blds[half] + (wc * 64 + row16) * 32 + kq * 8;
      bf16x8 af[4], bfr[4];
#pragma unroll
      for (int mf = 0; mf < 4; ++mf) af[mf] = *reinterpret_cast<const bf16x8*>(Ab + mf * 16 * 32);
#pragma unroll
      for (int nf = 0; nf < 4; ++nf) bfr[nf] = *reinterpret_cast<const bf16x8*>(Bb + nf * 16 * 32);
#pragma unroll
      for (int mf = 0; mf < 4; ++mf)
#pragma unroll
        for (int nf = 0; nf < 4; ++nf)
          acc[mf][nf] = __builtin_amdgcn_mfma_f32_16x16x32_bf16(af[mf], bfr[nf], acc[mf][nf], 0, 0, 0);
    }
    __syncthreads();
  }

#pragma unroll
  for (int mf = 0; mf < 4; ++mf) {
#pragma unroll
    for (int nf = 0; nf < 4; ++nf) {
      const int n = n0 + wc * 64 + nf * 16 + row16;
      const float bs = bias[n];
#pragma unroll
      for (int r = 0; r < 4; ++r) {
        const int t = t0 + wr * 64 + mf * 16 + kq * 4 + r;
        out[(size_t)t * NDIM + n] = acc[mf][nf][r] + bs;
      }
    }
  }
}

// ---------------- Scan pass2 (cross-chunk) + pass3 (replay) ----------------
__global__ void scan_pass2(const float* __restrict__ aggA, const float* __restrict__ aggB,
                           float* __restrict__ pref) {
  const int d0 = blockIdx.x * 512 + threadIdx.x * 2;
  float p0 = 0.0f, p1 = 0.0f;
#pragma unroll 8
  for (int c = 0; c < NCHUNK; ++c) {
    const float2 A = *reinterpret_cast<const float2*>(aggA + c * DHID + d0);
    const float2 B = *reinterpret_cast<const float2*>(aggB + c * DHID + d0);
    p0 = fmaf(A.x, p0, B.x);
    p1 = fmaf(A.y, p1, B.y);
    *reinterpret_cast<float2*>(pref + c * DHID + d0) = make_float2(p0, p1);
  }
}

__global__ void scan_pass3(const unsigned int* __restrict__ pack, const float* __restrict__ pref,
                           unsigned int* __restrict__ hbf2 /* 2x bf16 per uint */) {
  const int d0 = blockIdx.y * 512 + threadIdx.x * 2;
  const int c = blockIdx.x;
  float h0, h1;
  if (c == 0) {
    h0 = 0.0f;
    h1 = 0.0f;
  } else {
    const float2 pv = *reinterpret_cast<const float2*>(pref + (c - 1) * DHID + d0);
    h0 = pv.x;
    h1 = pv.y;
  }
  const size_t base = (size_t)c * CLEN * DHID + d0;
#pragma unroll 4
  for (int t = 0; t < CLEN; ++t) {
    const uint2 v = *reinterpret_cast<const uint2*>(pack + base + (size_t)t * DHID);
    const float a0 = 1.0f - bf16tof(v.x & 0xffffu);
    const float a1 = 1.0f - bf16tof(v.y & 0xffffu);
    h0 = fmaf(a0, h0, bf16tof(v.x >> 16));
    h1 = fmaf(a1, h1, bf16tof(v.y >> 16));
    hbf2[(base + (size_t)t * DHID) >> 1] = ((unsigned int)bf16r(h1) << 16) | (unsigned int)bf16r(h0);
  }
}

extern "C" void kernel_launch(void* const* d_in, const int* in_sizes, int n_in,
                              void* d_out, int out_size, void* d_ws, size_t ws_size,
                              hipStream_t stream) {
  const float* inputs = (const float*)d_in[0];
  const float* pre_a = (const float*)d_in[1];
  const float* Wr = (const float*)d_in[2];
  const float* br = (const float*)d_in[3];
  const float* Wi = (const float*)d_in[4];
  const float* bi = (const float*)d_in[5];
  const float* Wx = (const float*)d_in[6];
  const float* bx = (const float*)d_in[7];
  const float* Wo = (const float*)d_in[8];
  const float* bo = (const float*)d_in[9];
  float* out = (float*)d_out;

  char* ws = (char*)d_ws;
  size_t off = 0;
  auto alloc = [&](size_t bytes) {
    char* p = ws + off;
    off += (bytes + 255) & ~(size_t)255;
    return p;
  };
  unsigned short* Xbf = (unsigned short*)alloc((size_t)TT * DIN * 2);
  unsigned short* Wrbf = (unsigned short*)alloc((size_t)DHID * DIN * 2);
  unsigned short* Wibf = (unsigned short*)alloc((size_t)DHID * DIN * 2);
  unsigned short* Wxbf = (unsigned short*)alloc((size_t)DHID * DIN * 2);
  unsigned short* Wobf = (unsigned short*)alloc((size_t)DOUT * DHID * 2);
  unsigned int* pack = (unsigned int*)alloc((size_t)TT * DHID * 4);
  unsigned short* hbf = (unsigned short*)alloc((size_t)TT * DHID * 2);
  float* dec = (float*)alloc(DHID * 4);
  float* aggA = (float*)alloc((size_t)NCHUNK * DHID * 4);
  float* aggB = (float*)alloc((size_t)NCHUNK * DHID * 4);
  float* pref = (float*)alloc((size_t)NCHUNK * DHID * 4);
  if (off > ws_size) return;  // workspace too small: fail visibly

  // Casts to bf16
  cast_f32_bf16<<<TT * DIN / 4 / 256, 256, 0, stream>>>(inputs, Xbf, TT * DIN / 4);
  cast_w4<<<dim3(DHID * DIN / 4 / 256, 4), 256, 0, stream>>>(Wr, Wi, Wx, Wo, Wrbf, Wibf, Wxbf, Wobf);
  dec_kernel<<<DHID / 256, 256, 0, stream>>>(pre_a, dec);

  // Fused gate GEMM + nonlinearity + chunk aggregates -> pack, aggA, aggB
  gemm_gates<<<dim3(DHID / 64, TT / 128), 256, 0, stream>>>(Xbf, Wrbf, Wibf, Wxbf, br, bi, bx, dec,
                                                            pack, aggA, aggB);

  // Cross-chunk scan + replay
  scan_pass2<<<DHID / 512, 256, 0, stream>>>(aggA, aggB, pref);
  scan_pass3<<<dim3(NCHUNK, DHID / 512), 256, 0, stream>>>(pack, pref, (unsigned int*)hbf);

  // Output projection
  gemm_bt<DHID, DOUT><<<dim3(DOUT / 128, TT / 128), 256, 0, stream>>>(hbf, Wobf, bo, out);
}

// Round 11
// 229.370 us; speedup vs baseline: 1.8873x; 1.8873x over previous
//
#include <hip/hip_runtime.h>
#include <cstdint>
#include <cstddef>

#define TT 8192
#define DIN 1024
#define DHID 2048
#define DOUT 1024
#define NCHUNK 128
#define CLEN 64   // TT / NCHUNK
#define GBUF 10240  // elems per 20 KB gate sub-tile buffer (A 8KB + 3xB 4KB)

typedef __bf16 bf16x8 __attribute__((ext_vector_type(8)));
typedef float f32x4 __attribute__((ext_vector_type(4)));
using u32_as1 = __attribute__((address_space(1))) const unsigned int;
using u32_as3 = __attribute__((address_space(3))) unsigned int;

__device__ __forceinline__ unsigned short bf16r(float x) {
  unsigned int u = __float_as_uint(x);
  u += 0x7fffu + ((u >> 16) & 1u);
  return (unsigned short)(u >> 16);
}

__device__ __forceinline__ float bf16tof(unsigned int u) {
  return __uint_as_float(u << 16);
}

// ---------------- Single prep dispatch: X cast + 4 weight casts + dec ----------------
// b < 8192            : X cast (2,097,152 float4s)
// 8192 <= b < 16384   : weight casts, w = (b-8192)>>11, 2048 blocks each (524,288 float4s)
// 16384 <= b < 16392  : dec[d] = -8*softplus(pre_a[d])
__global__ void prep_all(const float* __restrict__ X, const float* __restrict__ W0,
                         const float* __restrict__ W1, const float* __restrict__ W2,
                         const float* __restrict__ W3, const float* __restrict__ pre_a,
                         unsigned short* __restrict__ Xb, unsigned short* __restrict__ D0,
                         unsigned short* __restrict__ D1, unsigned short* __restrict__ D2,
                         unsigned short* __restrict__ D3, float* __restrict__ dec) {
  const int b = blockIdx.x;
  if (b < 8192) {
    const int i = b * 256 + threadIdx.x;
    const float4 v = reinterpret_cast<const float4*>(X)[i];
    ushort4 o;
    o.x = bf16r(v.x);
    o.y = bf16r(v.y);
    o.z = bf16r(v.z);
    o.w = bf16r(v.w);
    reinterpret_cast<ushort4*>(Xb)[i] = o;
  } else if (b < 16384) {
    const int w = (b - 8192) >> 11;
    const float* s = (w == 0) ? W0 : ((w == 1) ? W1 : ((w == 2) ? W2 : W3));
    unsigned short* d = (w == 0) ? D0 : ((w == 1) ? D1 : ((w == 2) ? D2 : D3));
    const int i = ((b - 8192) & 2047) * 256 + threadIdx.x;
    const float4 v = reinterpret_cast<const float4*>(s)[i];
    ushort4 o;
    o.x = bf16r(v.x);
    o.y = bf16r(v.y);
    o.z = bf16r(v.z);
    o.w = bf16r(v.w);
    reinterpret_cast<ushort4*>(d)[i] = o;
  } else {
    const int d = (b - 16384) * 256 + threadIdx.x;
    if (d < DHID) dec[d] = -8.0f * log1pf(expf(pre_a[d]));
  }
}

// ---------------- Fused gate GEMM (round-8 GOLDEN body — FINAL, do not restructure) ----------------
// 5 structural experiments (r3,r4,r6,r9,r10) all regressed via accumulator spill or the
// VGPR=128 occupancy cliff. This exact body: 142 µs, VGPR 128, MfmaUtil ~31%, MFMA+VALU
// issue ~89% combined. 2 BK=32 sub-tiles per barrier period, single-buffered.
__global__ __launch_bounds__(256) void gemm_gates(
    const unsigned short* __restrict__ X, const unsigned short* __restrict__ Wr,
    const unsigned short* __restrict__ Wi, const unsigned short* __restrict__ Wx,
    const float* __restrict__ br, const float* __restrict__ bi, const float* __restrict__ bx,
    const float* __restrict__ dec, unsigned int* __restrict__ pack_out) {
  __shared__ __align__(16) unsigned short lds[2 * GBUF];  // 2 sub-tiles x 20 KB
  const int n0 = blockIdx.x * 64;
  const int t0 = blockIdx.y * 128;
  const int tid = threadIdx.x;
  const int wave = tid >> 6, lane = tid & 63;
  const int wr = wave >> 1, wc = wave & 1;
  const int row16 = lane & 15, kq = lane >> 4;

  f32x4 acc[3][4][2] = {};

  for (int k0 = 0; k0 < DIN; k0 += 64) {
    // Stage BOTH sub-tiles (k0, k0+32): 40 segs of 1 KiB, wave w owns segs 10w..10w+9.
#pragma unroll
    for (int s = 0; s < 10; ++s) {
      const int sg = wave * 10 + s;
      const int half = (sg >= 20);
      const int seg = sg - half * 20;
      const int kk = k0 + half * 32;
      unsigned short* dst = lds + half * GBUF;
      const int lb = lane * 16;
      if (seg < 8) {
        const int off = seg * 1024 + lb;
        const int row = off >> 6, ke = (off & 63) >> 1;
        __builtin_amdgcn_global_load_lds((u32_as1*)(X + (size_t)(t0 + row) * DIN + kk + ke),
                                         (u32_as3*)(dst + seg * 512), 16, 0, 0);
      } else {
        const int m = (seg - 8) >> 2, sub = (seg - 8) & 3;
        const unsigned short* Bm = (m == 0) ? Wr : ((m == 1) ? Wi : Wx);
        const int off = sub * 1024 + lb;
        const int row = off >> 6, ke = (off & 63) >> 1;
        __builtin_amdgcn_global_load_lds((u32_as1*)(Bm + (size_t)(n0 + row) * DIN + kk + ke),
                                         (u32_as3*)(dst + (128 + m * 64) * 32 + sub * 512), 16, 0, 0);
      }
    }
    __syncthreads();

#pragma unroll
    for (int half = 0; half < 2; ++half) {
      const unsigned short* hb = lds + half * GBUF;
      const unsigned short* Ab = hb + (wr * 64 + row16) * 32 + kq * 8;
      bf16x8 af[4];
#pragma unroll
      for (int mf = 0; mf < 4; ++mf) af[mf] = *reinterpret_cast<const bf16x8*>(Ab + mf * 16 * 32);
#pragma unroll
      for (int z = 0; z < 3; ++z) {
        const unsigned short* Bb = hb + (128 + z * 64 + wc * 32 + row16) * 32 + kq * 8;
        const bf16x8 b0 = *reinterpret_cast<const bf16x8*>(Bb);
        const bf16x8 b1 = *reinterpret_cast<const bf16x8*>(Bb + 16 * 32);
#pragma unroll
        for (int mf = 0; mf < 4; ++mf) {
          acc[z][mf][0] = __builtin_amdgcn_mfma_f32_16x16x32_bf16(af[mf], b0, acc[z][mf][0], 0, 0, 0);
          acc[z][mf][1] = __builtin_amdgcn_mfma_f32_16x16x32_bf16(af[mf], b1, acc[z][mf][1], 0, 0, 0);
        }
      }
    }
    __syncthreads();
  }

  // Epilogue: C/D layout col = lane&15, row = (lane>>4)*4 + reg (m89-verified)
  // om = 1-a stored bf16: |da| <= 0.004*(1-a) -> scan h error ~3e-4 RMS (safe).
#pragma unroll
  for (int nf = 0; nf < 2; ++nf) {
    const int n = n0 + wc * 32 + nf * 16 + row16;
    const float brv = br[n], biv = bi[n], bxv = bx[n], dcv = dec[n];
#pragma unroll
    for (int mf = 0; mf < 4; ++mf) {
#pragma unroll
      for (int r = 0; r < 4; ++r) {
        const int t = t0 + wr * 64 + mf * 16 + kq * 4 + r;
        const float rp = acc[0][mf][nf][r] + brv;
        const float ip = acc[1][mf][nf][r] + biv;
        const float xv = acc[2][mf][nf][r] + bxv;
        const float rs = __builtin_amdgcn_rcpf(1.0f + __expf(-rp));
        const float av = __expf(dcv * rs);
        const float is = __builtin_amdgcn_rcpf(1.0f + __expf(-ip));
        const float gv = sqrtf(fmaxf(0.0f, 1.0f - av * av)) * (is * xv);
        const float om = 1.0f - av;
        pack_out[(size_t)t * DHID + n] = ((unsigned int)bf16r(gv) << 16) | (unsigned int)bf16r(om);
      }
    }
  }
}

// ---------------- Output projection GEMM (round-8 proven body) ----------------
template <int KDIM, int NDIM>
__global__ __launch_bounds__(256) void gemm_bt(const unsigned short* __restrict__ A,
                                               const unsigned short* __restrict__ B,
                                               const float* __restrict__ bias,
                                               float* __restrict__ out) {
  __shared__ __align__(16) unsigned short Alds[2][128 * 32];
  __shared__ __align__(16) unsigned short Blds[2][128 * 32];
  const int n0 = blockIdx.x * 128;
  const int t0 = blockIdx.y * 128;
  const int tid = threadIdx.x;
  const int wave = tid >> 6, lane = tid & 63;
  const int wr = wave >> 1, wc = wave & 1;
  const int row16 = lane & 15, kq = lane >> 4;

  f32x4 acc[4][4] = {};

  for (int k0 = 0; k0 < KDIM; k0 += 64) {
#pragma unroll
    for (int half = 0; half < 2; ++half) {
      const int kk = k0 + half * 32;
#pragma unroll
      for (int s = 0; s < 2; ++s) {
        const int seg = wave * 2 + s;
        const int off = seg * 1024 + lane * 16;
        const int row = off >> 6;
        const int ke = (off & 63) >> 1;
        __builtin_amdgcn_global_load_lds((u32_as1*)(A + (size_t)(t0 + row) * KDIM + kk + ke),
                                         (u32_as3*)(Alds[half] + seg * 512), 16, 0, 0);
        __builtin_amdgcn_global_load_lds((u32_as1*)(B + (size_t)(n0 + row) * KDIM + kk + ke),
                                         (u32_as3*)(Blds[half] + seg * 512), 16, 0, 0);
      }
    }
    __syncthreads();

#pragma unroll
    for (int half = 0; half < 2; ++half) {
      const unsigned short* Ab = Alds[half] + (wr * 64 + row16) * 32 + kq * 8;
      const unsigned short* Bb = Blds[half] + (wc * 64 + row16) * 32 + kq * 8;
      bf16x8 af[4], bfr[4];
#pragma unroll
      for (int mf = 0; mf < 4; ++mf) af[mf] = *reinterpret_cast<const bf16x8*>(Ab + mf * 16 * 32);
#pragma unroll
      for (int nf = 0; nf < 4; ++nf) bfr[nf] = *reinterpret_cast<const bf16x8*>(Bb + nf * 16 * 32);
#pragma unroll
      for (int mf = 0; mf < 4; ++mf)
#pragma unroll
        for (int nf = 0; nf < 4; ++nf)
          acc[mf][nf] = __builtin_amdgcn_mfma_f32_16x16x32_bf16(af[mf], bfr[nf], acc[mf][nf], 0, 0, 0);
    }
    __syncthreads();
  }

#pragma unroll
  for (int mf = 0; mf < 4; ++mf) {
#pragma unroll
    for (int nf = 0; nf < 4; ++nf) {
      const int n = n0 + wc * 64 + nf * 16 + row16;
      const float bs = bias[n];
#pragma unroll
      for (int r = 0; r < 4; ++r) {
        const int t = t0 + wr * 64 + mf * 16 + kq * 4 + r;
        out[(size_t)t * NDIM + n] = acc[mf][nf][r] + bs;
      }
    }
  }
}

// ---------------- Chunked scan over packed (gx|om): h_t = (1-om)*h_{t-1} + gx ----------------
__global__ void scan_pass1(const unsigned int* __restrict__ pack,
                           float* __restrict__ aggA, float* __restrict__ aggB) {
  const int d0 = blockIdx.y * 512 + threadIdx.x * 2;
  const int c = blockIdx.x;
  const size_t base = (size_t)c * CLEN * DHID + d0;
  float h0 = 0.0f, h1 = 0.0f, p0 = 1.0f, p1 = 1.0f;
#pragma unroll 4
  for (int t = 0; t < CLEN; ++t) {
    const uint2 v = *reinterpret_cast<const uint2*>(pack + base + (size_t)t * DHID);
    const float a0 = 1.0f - bf16tof(v.x & 0xffffu);
    const float a1 = 1.0f - bf16tof(v.y & 0xffffu);
    h0 = fmaf(a0, h0, bf16tof(v.x >> 16));
    h1 = fmaf(a1, h1, bf16tof(v.y >> 16));
    p0 *= a0;
    p1 *= a1;
  }
  *reinterpret_cast<float2*>(aggA + c * DHID + d0) = make_float2(p0, p1);
  *reinterpret_cast<float2*>(aggB + c * DHID + d0) = make_float2(h0, h1);
}

__global__ void scan_pass2(const float* __restrict__ aggA, const float* __restrict__ aggB,
                           float* __restrict__ pref) {
  const int d0 = blockIdx.x * 512 + threadIdx.x * 2;
  float p0 = 0.0f, p1 = 0.0f;
#pragma unroll 8
  for (int c = 0; c < NCHUNK; ++c) {
    const float2 A = *reinterpret_cast<const float2*>(aggA + c * DHID + d0);
    const float2 B = *reinterpret_cast<const float2*>(aggB + c * DHID + d0);
    p0 = fmaf(A.x, p0, B.x);
    p1 = fmaf(A.y, p1, B.y);
    *reinterpret_cast<float2*>(pref + c * DHID + d0) = make_float2(p0, p1);
  }
}

__global__ void scan_pass3(const unsigned int* __restrict__ pack, const float* __restrict__ pref,
                           unsigned int* __restrict__ hbf2 /* 2x bf16 per uint */) {
  const int d0 = blockIdx.y * 512 + threadIdx.x * 2;
  const int c = blockIdx.x;
  float h0, h1;
  if (c == 0) {
    h0 = 0.0f;
    h1 = 0.0f;
  } else {
    const float2 pv = *reinterpret_cast<const float2*>(pref + (c - 1) * DHID + d0);
    h0 = pv.x;
    h1 = pv.y;
  }
  const size_t base = (size_t)c * CLEN * DHID + d0;
#pragma unroll 4
  for (int t = 0; t < CLEN; ++t) {
    const uint2 v = *reinterpret_cast<const uint2*>(pack + base + (size_t)t * DHID);
    const float a0 = 1.0f - bf16tof(v.x & 0xffffu);
    const float a1 = 1.0f - bf16tof(v.y & 0xffffu);
    h0 = fmaf(a0, h0, bf16tof(v.x >> 16));
    h1 = fmaf(a1, h1, bf16tof(v.y >> 16));
    hbf2[(base + (size_t)t * DHID) >> 1] = ((unsigned int)bf16r(h1) << 16) | (unsigned int)bf16r(h0);
  }
}

extern "C" void kernel_launch(void* const* d_in, const int* in_sizes, int n_in,
                              void* d_out, int out_size, void* d_ws, size_t ws_size,
                              hipStream_t stream) {
  const float* inputs = (const float*)d_in[0];
  const float* pre_a = (const float*)d_in[1];
  const float* Wr = (const float*)d_in[2];
  const float* br = (const float*)d_in[3];
  const float* Wi = (const float*)d_in[4];
  const float* bi = (const float*)d_in[5];
  const float* Wx = (const float*)d_in[6];
  const float* bx = (const float*)d_in[7];
  const float* Wo = (const float*)d_in[8];
  const float* bo = (const float*)d_in[9];
  float* out = (float*)d_out;

  char* ws = (char*)d_ws;
  size_t off = 0;
  auto alloc = [&](size_t bytes) {
    char* p = ws + off;
    off += (bytes + 255) & ~(size_t)255;
    return p;
  };
  unsigned short* Xbf = (unsigned short*)alloc((size_t)TT * DIN * 2);
  unsigned short* Wrbf = (unsigned short*)alloc((size_t)DHID * DIN * 2);
  unsigned short* Wibf = (unsigned short*)alloc((size_t)DHID * DIN * 2);
  unsigned short* Wxbf = (unsigned short*)alloc((size_t)DHID * DIN * 2);
  unsigned short* Wobf = (unsigned short*)alloc((size_t)DOUT * DHID * 2);
  unsigned int* pack = (unsigned int*)alloc((size_t)TT * DHID * 4);
  unsigned short* hbf = (unsigned short*)alloc((size_t)TT * DHID * 2);
  float* dec = (float*)alloc(DHID * 4);
  float* aggA = (float*)alloc((size_t)NCHUNK * DHID * 4);
  float* aggB = (float*)alloc((size_t)NCHUNK * DHID * 4);
  float* pref = (float*)alloc((size_t)NCHUNK * DHID * 4);
  if (off > ws_size) return;  // workspace too small: fail visibly

  // Single prep dispatch: X cast + 4 weight casts + dec
  prep_all<<<16392, 256, 0, stream>>>(inputs, Wr, Wi, Wx, Wo, pre_a, Xbf, Wrbf, Wibf, Wxbf, Wobf,
                                      dec);

  // Fused gate GEMM + nonlinearity -> packed (gx|om)
  gemm_gates<<<dim3(DHID / 64, TT / 128), 256, 0, stream>>>(Xbf, Wrbf, Wibf, Wxbf, br, bi, bx, dec,
                                                            pack);

  // Chunked scan
  scan_pass1<<<dim3(NCHUNK, DHID / 512), 256, 0, stream>>>(pack, aggA, aggB);
  scan_pass2<<<DHID / 512, 256, 0, stream>>>(aggA, aggB, pref);
  scan_pass3<<<dim3(NCHUNK, DHID / 512), 256, 0, stream>>>(pack, pref, (unsigned int*)hbf);

  // Output projection
  gemm_bt<DHID, DOUT><<<dim3(DOUT / 128, TT / 128), 256, 0, stream>>>(hbf, Wobf, bo, out);
}